// Round 1
// baseline (1111.210 us; speedup 1.0000x reference)
//
#include <hip/hip_runtime.h>
#include <stdint.h>

#define DI __device__ __forceinline__

constexpr int Bn = 32, Cc = 64, Wn = 96, Hn = 96, Ln = 32, NG = 128, OUTC = 256;
constexpr int SEQ = 96;
constexpr long long NPIX = (long long)Bn * Wn * Hn;   // 294912
constexpr int GRAM_BLOCKS = 128;
constexpr int PIX_PER_BLOCK = (int)(NPIX / GRAM_BLOCKS); // 2304

DI float sigmf(float x) { return 1.0f / (1.0f + __expf(-x)); }
DI float tanhf_(float x) { return 1.0f - 2.0f / (__expf(2.0f * x) + 1.0f); } // NaN-free both tails
DI float bf2f(unsigned short u) { return __uint_as_float(((unsigned)u) << 16); }
DI unsigned short f2bf(float f) {
    unsigned u = __float_as_uint(f);
    u += 0x7FFFu + ((u >> 16) & 1u);   // RNE
    return (unsigned short)(u >> 16);
}
DI float d4(float4 a, float4 b, float acc) {
    acc = fmaf(a.x, b.x, acc); acc = fmaf(a.y, b.y, acc);
    acc = fmaf(a.z, b.z, acc); acc = fmaf(a.w, b.w, acc); return acc;
}

// ---------------------------------------------------------------------------
// BiLSTM pass. VERT=1: input x [B,C,W,H], chain=(b,w), seq over h, out f32
//                      v[b,h,w,0:32]=fwd, [32:64]=bwd   (layout [B,H,W,64])
// VERT=0: input v [B,H,W,64], chain=(b,h), seq over w, out bf16
//                      hh[b,h,w,0:32]/[32:64]           (layout [B,H,W,64])
// Block: 256 threads; waves 0-1 forward dir, waves 2-3 backward dir.
// Thread owns gate row g = tid&127 with its 96 weight values in VGPRs.
// ---------------------------------------------------------------------------
template<int VERT>
__global__ __launch_bounds__(256)
void lstm_kernel(const float* __restrict__ in,
                 const float* __restrict__ wih_f, const float* __restrict__ whh_f,
                 const float* __restrict__ bih_f, const float* __restrict__ bhh_f,
                 const float* __restrict__ wih_b, const float* __restrict__ whh_b,
                 const float* __restrict__ bih_b, const float* __restrict__ bhh_b,
                 void* __restrict__ outv)
{
    __shared__ float xs[SEQ][64];    // staged input slab (transposed for VERT)
    __shared__ float hsh[2][32];     // per-dir hidden state
    __shared__ float gsh[2][NG];     // per-dir gate pre-activations

    const int tid = threadIdx.x;
    const int b = blockIdx.x / 96, q = blockIdx.x % 96;
    const int dir = tid >> 7, g = tid & 127;

    const float* wih = dir ? wih_b : wih_f;
    const float* whh = dir ? whh_b : whh_f;
    const float bias = dir ? (bih_b[g] + bhh_b[g]) : (bih_f[g] + bhh_f[g]);

    float4 wi[16], wh[8];
    const float4* wip = (const float4*)(wih + g * 64);
#pragma unroll
    for (int k = 0; k < 16; ++k) wi[k] = wip[k];
    const float4* whp = (const float4*)(whh + g * 32);
#pragma unroll
    for (int k = 0; k < 8; ++k) wh[k] = whp[k];

    if (VERT) {
        // x[b,c,w=q,h]: read float4 along h (coalesced rows), transpose into xs[h][c]
        for (int i4 = tid; i4 < 1536; i4 += 256) {
            int c = i4 & 63, h4 = i4 >> 6;
            float4 v = *(const float4*)(in + (((size_t)b * 64 + c) * 96 + q) * 96 + 4 * h4);
            xs[4 * h4 + 0][c] = v.x; xs[4 * h4 + 1][c] = v.y;
            xs[4 * h4 + 2][c] = v.z; xs[4 * h4 + 3][c] = v.w;
        }
    } else {
        // v[b,h=q,:,:] is a contiguous 96x64 slab
        const float4* src = (const float4*)(in + (size_t)(b * 96 + q) * (96 * 64));
        float4* dst = (float4*)&xs[0][0];
        for (int i4 = tid; i4 < 1536; i4 += 256) dst[i4] = src[i4];
    }
    if (tid < 64) hsh[tid >> 5][tid & 31] = 0.0f;
    __syncthreads();

    float cst = 0.0f;  // cell state, owned by threads with g<32
    for (int t = 0; t < SEQ; ++t) {
        const int te = dir ? (SEQ - 1 - t) : t;
        float acc = bias;
        const float4* xt = (const float4*)xs[te];
#pragma unroll
        for (int k = 0; k < 16; ++k) acc = d4(wi[k], xt[k], acc);
        const float4* hv = (const float4*)hsh[dir];
#pragma unroll
        for (int k = 0; k < 8; ++k) acc = d4(wh[k], hv[k], acc);
        gsh[dir][g] = acc;
        __syncthreads();
        if (g < 32) {
            float ig = sigmf(gsh[dir][g]);
            float fg = sigmf(gsh[dir][32 + g]);
            float gg = tanhf_(gsh[dir][64 + g]);
            float og = sigmf(gsh[dir][96 + g]);
            cst = fmaf(fg, cst, ig * gg);
            float hval = og * tanhf_(cst);
            hsh[dir][g] = hval;
            if (VERT) {
                ((float*)outv)[(((size_t)b * 96 + te) * 96 + q) * 64 + dir * 32 + g] = hval;
            } else {
                ((unsigned short*)outv)[(((size_t)b * 96 + q) * 96 + te) * 64 + dir * 32 + g] = f2bf(hval);
            }
        }
        __syncthreads();
    }
}

// ---------------------------------------------------------------------------
// Partial Gram (64x64) + channel-sum (64) of hh over this block's pixel chunk.
// Per-lane 8x8 register tile; block-local LDS reduction; deterministic output.
// ---------------------------------------------------------------------------
__global__ __launch_bounds__(256)
void gram_partial(const unsigned short* __restrict__ hh, float* __restrict__ part)
{
    __shared__ float xs[64][64];
    __shared__ float red[4160];
    const int tid = threadIdx.x;
    for (int e = tid; e < 4160; e += 256) red[e] = 0.0f;
    const int lane = tid & 63, wv = tid >> 6;
    const int li = lane >> 3, lj = lane & 7;
    float acc[8][8]; float macc[8];
#pragma unroll
    for (int i = 0; i < 8; ++i) {
        macc[i] = 0.f;
#pragma unroll
        for (int j = 0; j < 8; ++j) acc[i][j] = 0.f;
    }
    const size_t pix0 = (size_t)blockIdx.x * PIX_PER_BLOCK;
    for (int tile = 0; tile < PIX_PER_BLOCK / 64; ++tile) {
        __syncthreads();
        const unsigned short* src = hh + (pix0 + tile * 64) * 64;
#pragma unroll
        for (int r = 0; r < 4; ++r) {
            int idx4 = tid + 256 * r;
            ushort4 v = ((const ushort4*)src)[idx4];
            int fi = idx4 * 4; int px = fi >> 6; int c = fi & 63;
            xs[px][c] = bf2f(v.x); xs[px][c + 1] = bf2f(v.y);
            xs[px][c + 2] = bf2f(v.z); xs[px][c + 3] = bf2f(v.w);
        }
        __syncthreads();
        for (int p = wv * 16; p < wv * 16 + 16; ++p) {
            float4 ra = *(const float4*)&xs[p][8 * li];
            float4 rb = *(const float4*)&xs[p][8 * li + 4];
            float4 ca = *(const float4*)&xs[p][8 * lj];
            float4 cb = *(const float4*)&xs[p][8 * lj + 4];
            float r[8] = {ra.x, ra.y, ra.z, ra.w, rb.x, rb.y, rb.z, rb.w};
            float cl[8] = {ca.x, ca.y, ca.z, ca.w, cb.x, cb.y, cb.z, cb.w};
#pragma unroll
            for (int i = 0; i < 8; ++i) {
#pragma unroll
                for (int j = 0; j < 8; ++j) acc[i][j] = fmaf(r[i], cl[j], acc[i][j]);
            }
            if (lj == 0) {
#pragma unroll
                for (int i = 0; i < 8; ++i) macc[i] += r[i];
            }
        }
    }
    __syncthreads();
#pragma unroll
    for (int i = 0; i < 8; ++i)
#pragma unroll
        for (int j = 0; j < 8; ++j)
            atomicAdd(&red[(8 * li + i) * 64 + 8 * lj + j], acc[i][j]);
    if (lj == 0)
        for (int i = 0; i < 8; ++i) atomicAdd(&red[4096 + 8 * li + i], macc[i]);
    __syncthreads();
    for (int e = tid; e < 4160; e += 256) part[(size_t)blockIdx.x * 4160 + e] = red[e];
}

__global__ void gram_reduce(const float* __restrict__ part, float* __restrict__ M)
{
    int e = blockIdx.x * 256 + threadIdx.x;
    if (e >= 4160) return;
    double s = 0.0;
    for (int p = 0; p < GRAM_BLOCKS; ++p) s += (double)part[(size_t)p * 4160 + e];
    M[e] = (float)s;
}

// Per-output-channel affine coefficients A,B such that out = A*(w_o . u) + B
__global__ __launch_bounds__(256)
void stats_kernel(const float* __restrict__ M, const float* __restrict__ cw,
                  const float* __restrict__ cb, const float* __restrict__ bg,
                  const float* __restrict__ bb,
                  float* __restrict__ Aout, float* __restrict__ Bout)
{
    __shared__ float Ml[4160];
    const int tid = threadIdx.x;
    for (int e = tid; e < 4160; e += 256) Ml[e] = M[e];
    __syncthreads();
    float wr[64];
#pragma unroll
    for (int c = 0; c < 64; ++c) wr[c] = cw[tid * 64 + c];
    float s1 = 0.f;
#pragma unroll
    for (int c = 0; c < 64; ++c) s1 = fmaf(wr[c], Ml[4096 + c], s1);
    float s2 = 0.f;
    for (int c = 0; c < 64; ++c) {
        const float* Mr = &Ml[c * 64];
        float t = 0.f;
#pragma unroll
        for (int d = 0; d < 64; ++d) t = fmaf(wr[d], Mr[d], t);
        s2 = fmaf(wr[c], t, s2);
    }
    const double invN = 1.0 / (double)NPIX;
    double cbo = (double)cb[tid];
    double mu = (double)s1 * invN + cbo;
    double ey2 = (double)s2 * invN + 2.0 * cbo * ((double)s1 * invN) + cbo * cbo;
    double var = ey2 - mu * mu;
    double A = (double)bg[tid] / sqrt(var + 1e-5);
    Aout[tid] = (float)A;
    Bout[tid] = (float)((double)bb[tid] + A * (cbo - mu));
}

// ---------------------------------------------------------------------------
// Fused 1x1 conv + BN apply. Block = (b,w); thread = output channel o.
// out[b,o,w,h] = A_o * (w_o . hh[b,h,w,:]) + B_o
// ---------------------------------------------------------------------------
__global__ __launch_bounds__(256)
void conv_bn_kernel(const unsigned short* __restrict__ hh, const float* __restrict__ cw,
                    const float* __restrict__ Aarr, const float* __restrict__ Barr,
                    float* __restrict__ out)
{
    __shared__ float us[96][64];
    const int tid = threadIdx.x;
    const int b = blockIdx.x / 96, w = blockIdx.x % 96;
    for (int idx4 = tid; idx4 < 1536; idx4 += 256) {
        int fi = idx4 * 4; int hrow = fi >> 6; int c = fi & 63;
        ushort4 v = *(const ushort4*)(hh + ((size_t)(b * 96 + hrow) * 96 + w) * 64 + c);
        us[hrow][c] = bf2f(v.x); us[hrow][c + 1] = bf2f(v.y);
        us[hrow][c + 2] = bf2f(v.z); us[hrow][c + 3] = bf2f(v.w);
    }
    __syncthreads();
    float4 wreg[16];
    const float4* wp = (const float4*)(cw + tid * 64);
#pragma unroll
    for (int k = 0; k < 16; ++k) wreg[k] = wp[k];
    const float Ao = Aarr[tid], Bo = Barr[tid];
    float* obase = out + (((size_t)b * 256 + tid) * 96 + w) * 96;
    for (int h0 = 0; h0 < 96; h0 += 4) {
        float rv[4];
#pragma unroll
        for (int j = 0; j < 4; ++j) {
            const float4* ur = (const float4*)us[h0 + j];
            float a = 0.f;
#pragma unroll
            for (int k = 0; k < 16; ++k) a = d4(wreg[k], ur[k], a);
            rv[j] = fmaf(Ao, a, Bo);
        }
        float4 res; res.x = rv[0]; res.y = rv[1]; res.z = rv[2]; res.w = rv[3];
        *(float4*)(obase + h0) = res;
    }
}

extern "C" void kernel_launch(void* const* d_in, const int* in_sizes, int n_in,
                              void* d_out, int out_size, void* d_ws, size_t ws_size,
                              hipStream_t stream)
{
    const float* x       = (const float*)d_in[0];
    const float* v_wih_f = (const float*)d_in[1];
    const float* v_whh_f = (const float*)d_in[2];
    const float* v_bih_f = (const float*)d_in[3];
    const float* v_bhh_f = (const float*)d_in[4];
    const float* v_wih_b = (const float*)d_in[5];
    const float* v_whh_b = (const float*)d_in[6];
    const float* v_bih_b = (const float*)d_in[7];
    const float* v_bhh_b = (const float*)d_in[8];
    const float* h_wih_f = (const float*)d_in[9];
    const float* h_whh_f = (const float*)d_in[10];
    const float* h_bih_f = (const float*)d_in[11];
    const float* h_bhh_f = (const float*)d_in[12];
    const float* h_wih_b = (const float*)d_in[13];
    const float* h_whh_b = (const float*)d_in[14];
    const float* h_bih_b = (const float*)d_in[15];
    const float* h_bhh_b = (const float*)d_in[16];
    const float* conv_w  = (const float*)d_in[17];
    const float* conv_b  = (const float*)d_in[18];
    const float* bn_g    = (const float*)d_in[19];
    const float* bn_b    = (const float*)d_in[20];
    float* out = (float*)d_out;

    // v (f32, [B,H,W,64] = 75.5 MB) lives in the tail of d_out: it is dead
    // before conv_bn writes that region (conv only reads hh + A/B).
    const size_t v_elems = (size_t)Bn * Hn * Wn * 64;   // 18,874,368
    float* v_buf = out + ((size_t)out_size - v_elems);  // offset 56,623,104

    // workspace layout (needs ~38 MB)
    unsigned short* hh = (unsigned short*)d_ws;                       // bf16 [B,H,W,64]
    char* wsb = (char*)d_ws;
    float* part = (float*)(wsb + 37748736);                           // 128 x 4160 f32
    float* M    = (float*)(wsb + 37748736 + 2129920);                 // 4160 f32
    float* Aarr = M + 4160;
    float* Barr = Aarr + 256;

    lstm_kernel<1><<<3072, 256, 0, stream>>>(x, v_wih_f, v_whh_f, v_bih_f, v_bhh_f,
                                             v_wih_b, v_whh_b, v_bih_b, v_bhh_b, (void*)v_buf);
    lstm_kernel<0><<<3072, 256, 0, stream>>>(v_buf, h_wih_f, h_whh_f, h_bih_f, h_bhh_f,
                                             h_wih_b, h_whh_b, h_bih_b, h_bhh_b, (void*)hh);
    gram_partial<<<GRAM_BLOCKS, 256, 0, stream>>>(hh, part);
    gram_reduce<<<17, 256, 0, stream>>>(part, M);
    stats_kernel<<<1, 256, 0, stream>>>(M, conv_w, conv_b, bn_g, bn_b, Aarr, Barr);
    conv_bn_kernel<<<3072, 256, 0, stream>>>(hh, conv_w, Aarr, Barr, out);
}